// Round 13
// baseline (605.200 us; speedup 1.0000x reference)
//
#include <hip/hip_runtime.h>
#include <hip/hip_bf16.h>
#include <math.h>

typedef __attribute__((ext_vector_type(8))) short short8;
typedef __attribute__((ext_vector_type(4))) float f32x4;
typedef unsigned short u16;
typedef unsigned int u32;

#define SQ 513
#define MPAD 4224
#define MV 4104
#define NHEADS 32
#define DKH 32
#define SVP 576   // padded s extent for vT
#define SQP 576   // padded q extent for ab tiles

// round-to-nearest-even f32 -> bf16 (as u16 bits)
static __device__ inline u16 f2bf(float f) {
  u32 u = __builtin_bit_cast(u32, f);
  u = (u + 0x7fffu + ((u >> 16) & 1u)) >> 16;
  return (u16)u;
}

// f32 -> fp16 bits (RTE)
static __device__ inline u16 f2h(float f) {
  _Float16 h = (_Float16)f;
  return __builtin_bit_cast(u16, h);
}
static __device__ inline float h2f(u16 b) {
  return (float)__builtin_bit_cast(_Float16, b);
}

static __device__ inline void gld16(const void* g, void* l) {
  __builtin_amdgcn_global_load_lds((__attribute__((address_space(1))) void*)g,
                                   (__attribute__((address_space(3))) void*)l,
                                   16, 0, 0);
}

static __device__ inline float gelu_f(float x) {
  return 0.5f * x * (1.f + erff(x * 0.70710678118654752f));
}

// ---------------- weight transpose + cast: in f32 [K][N] -> out bf16 [N][K] ----------------
__global__ __launch_bounds__(256) void transpose_cast_k(const float* __restrict__ in,
    u16* __restrict__ out, int K, int N, float scale)
{
  __shared__ float t[32][33];
  int n0 = blockIdx.x * 32, k0 = blockIdx.y * 32;
  int tx = threadIdx.x & 31, ty = threadIdx.x >> 5;
#pragma unroll
  for (int i = 0; i < 32; i += 8)
    t[ty + i][tx] = in[(size_t)(k0 + ty + i) * N + n0 + tx];
  __syncthreads();
#pragma unroll
  for (int i = 0; i < 32; i += 8)
    out[(size_t)(n0 + ty + i) * K + k0 + tx] = f2bf(t[tx][ty + i] * scale);
}

// ---------------- V transpose: qkv V-region -> vT[b][h][d][SVP] (bf16) ----------------
__global__ __launch_bounds__(256) void vtrans_k(const u16* __restrict__ qkv,
    u16* __restrict__ vT)
{
  __shared__ u16 t[32][33];
  int st = blockIdx.x * 32, h = blockIdx.y, b = blockIdx.z;
  int tx = threadIdx.x & 31, ty = threadIdx.x >> 5;
#pragma unroll
  for (int i = 0; i < 32; i += 8) {
    int s = st + ty + i;
    int sc = s > 512 ? 512 : s;  // clamp: pad region gets finite data
    t[ty + i][tx] = qkv[(size_t)(b * SQ + sc) * 3072 + 2048 + h * DKH + tx];
  }
  __syncthreads();
#pragma unroll
  for (int i = 0; i < 32; i += 8) {
    int d = ty + i;
    vT[(((size_t)b * NHEADS + h) * DKH + d) * SVP + st + tx] = t[tx][d];
  }
}

// ---------------- prep_ab: bake bias+relpos+mask into tiled fp16 abt[bh][9][SQP][64] ----------------
// grid (256 bh, 36 sq-chunks of 16); all edge masking baked in:
//   sq>512 or sk>512 -> -30000 (fp16-safe mask; exp(s-30000)=0) ; sq==0 or sk==0 -> base ;
//   else masked inner.
__global__ __launch_bounds__(256) void prep_ab(const float* __restrict__ attn_bias,
    const int* __restrict__ rel_pos, const float* __restrict__ rel_emb,
    u16* __restrict__ abt)
{
  int bh = blockIdx.x;
  int b = bh >> 5, h = bh & 31;
  int t = threadIdx.x;
  const float* brow_base = attn_bias + ((size_t)bh * SQ) * SQ;
#pragma unroll 1
  for (int rl = 0; rl < 16; ++rl) {
    int sq = blockIdx.y * 16 + rl;
#pragma unroll
    for (int cc = 0; cc < 3; ++cc) {
      int sk = t + cc * 256;          // 0..767
      if (sk >= SQP) continue;        // cc==2: only t<64 participate
      float ab;
      if (sq > 512 || sk > 512) ab = -30000.f;
      else {
        float base = brow_base[(size_t)sq * SQ + sk];
        if (sq == 0 || sk == 0) ab = base;
        else {
          int rp = rel_pos[((size_t)b * 512 + sq - 1) * 512 + sk - 1];
          float inner = base + rel_emb[(size_t)rp * NHEADS + h];
          ab = (rp <= 15 || inner < -1e8f) ? inner : 0.f;
          if (ab < -30000.f) ab = -30000.f;
        }
      }
      int kt = sk >> 6, kp = sk & 63;
      abt[(((size_t)bh * 9 + kt) * SQP + sq) * 64 + kp] = f2h(ab);
    }
  }
}

// ---------------- concat qkv bias (scale on bq) ----------------
__global__ __launch_bounds__(256) void prep_bias_k(const float* __restrict__ bq,
    const float* __restrict__ bk, const float* __restrict__ bv,
    float* __restrict__ out, float scale)
{
  int i = blockIdx.x * 256 + threadIdx.x;
  float v = (i < 1024) ? bq[i] * scale : ((i < 2048) ? bk[i - 1024] : bv[i - 2048]);
  out[i] = v;
}

// ---------------- layernorm: f32 [rows][1024] -> bf16 ----------------
__global__ __launch_bounds__(256) void ln_k(const float* __restrict__ in,
    const float* __restrict__ g, const float* __restrict__ b,
    u16* __restrict__ out)
{
  int row = blockIdx.x;
  float4 v = ((const float4*)(in + (size_t)row * 1024))[threadIdx.x];
  float s = v.x + v.y + v.z + v.w;
  float s2 = v.x * v.x + v.y * v.y + v.z * v.z + v.w * v.w;
#pragma unroll
  for (int d = 32; d; d >>= 1) { s += __shfl_xor(s, d, 64); s2 += __shfl_xor(s2, d, 64); }
  __shared__ float ps[4], ps2[4];
  int w = threadIdx.x >> 6;
  if ((threadIdx.x & 63) == 0) { ps[w] = s; ps2[w] = s2; }
  __syncthreads();
  s = ps[0] + ps[1] + ps[2] + ps[3];
  s2 = ps2[0] + ps2[1] + ps2[2] + ps2[3];
  float mean = s * (1.f / 1024.f);
  float var = s2 * (1.f / 1024.f) - mean * mean;
  float inv = rsqrtf(var + 1e-5f);
  float4 gv = ((const float4*)g)[threadIdx.x];
  float4 bv = ((const float4*)b)[threadIdx.x];
  ushort4 o;
  o.x = f2bf((v.x - mean) * inv * gv.x + bv.x);
  o.y = f2bf((v.y - mean) * inv * gv.y + bv.y);
  o.z = f2bf((v.z - mean) * inv * gv.z + bv.z);
  o.w = f2bf((v.w - mean) * inv * gv.w + bv.w);
  ((ushort4*)(out + (size_t)row * 1024))[threadIdx.x] = o;
}

// ---------------- bf16 GEMM: C[M][N] = A[M][K] @ Bw[N][K]^T + bias, epilogues ----------------
// EPI 0: bf16 store (all padded rows)        [QKV]
// EPI 2: gelu, bf16 store                    [FFN1]
// EPI 4: split-K=2 partial f32 store         [O-proj / FFN2 halves]
template <int EPI>
__global__ __launch_bounds__(256) void gemm_bt(const u16* __restrict__ A,
    const u16* __restrict__ Bw, const float* __restrict__ bias,
    const float* __restrict__ resid, void* __restrict__ outp,
    int N, int K, int nbx)
{
  __shared__ alignas(16) u16 sA[128 * 64];
  __shared__ alignas(16) u16 sB[128 * 64];
  int tid = threadIdx.x;
  int l = tid & 63, lg = l >> 4, li = l & 15;

  int bidx = blockIdx.x;
  int kbeg = 0, kend = K;
  float* pout = (float*)outp;
  if (EPI == 4) {
    int half = gridDim.x >> 1;
    int s = bidx >= half;
    bidx -= s * half;
    kbeg = s * (K >> 1);
    kend = kbeg + (K >> 1);
    pout += (size_t)s * MPAD * 1024;
  }
  int mb = bidx / nbx, nb = bidx % nbx;
  int m0 = mb * 128, n0 = nb * 128;
  int wv = tid >> 6;
  int wr = wv >> 1, wc = wv & 1;
  f32x4 acc[4][4] = {};
  int r_ = tid >> 3, c_ = (tid & 7) * 8;
  const u16* Ag = A + (size_t)(m0 + r_) * K + c_;
  const u16* Bg = Bw + (size_t)(n0 + r_) * K + c_;
  u16* sAb = sA + (tid & 192) * 8;   // wave-uniform staging base
  u16* sBb = sB + (tid & 192) * 8;

  for (int k0 = kbeg; k0 < kend; k0 += 64) {
    __syncthreads();
#pragma unroll
    for (int i = 0; i < 4; ++i) {
      gld16(Ag + (size_t)(i * 32) * K + k0, sAb + i * 2048);
      gld16(Bg + (size_t)(i * 32) * K + k0, sBb + i * 2048);
    }
    __syncthreads();
#pragma unroll
    for (int ks = 0; ks < 2; ++ks) {
      short8 af[4], bfr[4];
#pragma unroll
      for (int i = 0; i < 4; ++i)
        af[i] = *(const short8*)&sA[(64 * wr + 16 * i + li) * 64 + ks * 32 + lg * 8];
#pragma unroll
      for (int j = 0; j < 4; ++j)
        bfr[j] = *(const short8*)&sB[(64 * wc + 16 * j + li) * 64 + ks * 32 + lg * 8];
#pragma unroll
      for (int i = 0; i < 4; ++i)
#pragma unroll
        for (int j = 0; j < 4; ++j)
          acc[i][j] = __builtin_amdgcn_mfma_f32_16x16x32_bf16(af[i], bfr[j], acc[i][j], 0, 0, 0);
    }
  }

#pragma unroll
  for (int i = 0; i < 4; ++i) {
    int rb = m0 + 64 * wr + 16 * i + 4 * lg;
#pragma unroll
    for (int j = 0; j < 4; ++j) {
      int col = n0 + 64 * wc + 16 * j + li;
      float bia = (EPI == 4) ? 0.f : bias[col];
#pragma unroll
      for (int r = 0; r < 4; ++r) {
        int row = rb + r;
        float v = acc[i][j][r] + bia;
        if (EPI == 0) {
          ((u16*)outp)[(size_t)row * N + col] = f2bf(v);
        } else if (EPI == 2) {
          ((u16*)outp)[(size_t)row * N + col] = f2bf(gelu_f(v));
        } else {
          pout[(size_t)row * N + col] = v;
        }
      }
    }
  }
}

// ---------------- combine kernels ----------------
// O-proj: out = p0 + p1 + bo + x   (grid MV x 256)
__global__ __launch_bounds__(256) void oproj_combine(const float* __restrict__ part,
    float* __restrict__ out, const float* __restrict__ bo, const float* __restrict__ x)
{
  size_t idx = (size_t)blockIdx.x * 256 + threadIdx.x;
  const float4* p0 = (const float4*)part;
  const float4* p1 = (const float4*)(part + (size_t)MPAD * 1024);
  float4 a = p0[idx], b = p1[idx];
  float4 bb = ((const float4*)bo)[idx & 255];
  float4 xx = ((const float4*)x)[idx];
  a.x += b.x + bb.x + xx.x;
  a.y += b.y + bb.y + xx.y;
  a.z += b.z + bb.z + xx.z;
  a.w += b.w + bb.w + xx.w;
  ((float4*)out)[idx] = a;
}

// FFN2: out += p0 + p1 + b2   (grid MV x 256)
__global__ __launch_bounds__(256) void ffn2_combine(const float* __restrict__ part,
    float* __restrict__ out, const float* __restrict__ b2)
{
  size_t idx = (size_t)blockIdx.x * 256 + threadIdx.x;
  const float4* p0 = (const float4*)part;
  const float4* p1 = (const float4*)(part + (size_t)MPAD * 1024);
  float4 a = ((float4*)out)[idx];
  float4 x0 = p0[idx], x1 = p1[idx];
  float4 bb = ((const float4*)b2)[idx & 255];
  a.x += x0.x + x1.x + bb.x;
  a.y += x0.y + x1.y + bb.y;
  a.z += x0.z + x1.z + bb.z;
  a.w += x0.w + x1.w + bb.w;
  ((float4*)out)[idx] = a;
}

// ---------------- fused flash attention (precomputed fp16 ab tiles, swapped QK^T) ----------------
// grid: (b, h, qtile of 64); block 256 = 4 waves; each wave owns 16 q-rows.
// All bias/relpos/mask logic pre-baked into abt (fp16 tiles); per k-tile the 8-KB ab tile
// is staged into LDS via global_load_lds (contiguous stream) alongside K and V^T.
// QK^T computed SWAPPED: sc[f] = mfma(K, Q) -> D[row=k-local=16f+4lg+r][col=q=li], so a
// lane's 4 ab values are k-consecutive -> one 8B LDS read per f.
// R11/R12 BUG FIXED HERE: the ab LDS row is the BLOCK-level q-row (16*wv + li), not li —
// waves 1..3 were reading wave-0's bias rows (identical absmax 0.209 in both rounds,
// bounded by softmax convexity — the fingerprint of a layout bug, not quantization).
__global__ __launch_bounds__(256) void attn_fused(const u16* __restrict__ qkv,
    const u16* __restrict__ vT, const u16* __restrict__ abt,
    u16* __restrict__ o)
{
  __shared__ alignas(16) u16 k_lds[2][64 * 32];
  __shared__ alignas(16) u16 v_lds[2][32 * 64];
  __shared__ alignas(16) u16 ab_lds[2][64 * 64];
  __shared__ alignas(16) u16 p_lds[4][16][72];
  __shared__ float l_lds[4][16];
  int bid = blockIdx.x;
  int qt = bid % 9, h = (bid / 9) % NHEADS, b = bid / (9 * NHEADS);
  int tid = threadIdx.x, wv = tid >> 6, l = tid & 63, lg = l >> 4, li = l & 15;
  int q0 = qt * 64;
  int sqb = q0 + 16 * wv + 4 * lg;

  // Q fragment (B operand now; same register layout): col = li (q), k(d) = lg*8+e
  short8 qfrag = *(const short8*)(qkv + (size_t)(b * SQ + q0 + 16 * wv + li) * 3072 + h * DKH + lg * 8);

  // --- staging coords (global_load_lds: dest = lds_base + tid*16B, linear) ---
  int krow = tid >> 2;
  int kchunk = (tid & 3) ^ ((tid >> 3) & 3);
  const u16* ksrc = qkv + (size_t)(b * SQ) * 3072 + 1024 + h * DKH + kchunk * 8;  // + s*3072
  int vrow = tid >> 3;
  int vchunk = (tid & 7) ^ (vrow & 7);
  const u16* vsrc = vT + (((size_t)b * NHEADS + h) * DKH + vrow) * SVP + vchunk * 8;  // + kt*64
  // ab tile: 512 chunks; thread stages dest chunks tid and tid+256; read-side XOR swizzle
  // (chunk-in-row ^ (row&7)) -> source pre-swizzled; second round = +32 rows (row&7 invariant).
  int abrow = tid >> 3;
  int abcir = (tid & 7) ^ (abrow & 7);
  const u16* absrc0 = abt + ((size_t)(b * NHEADS + h) * 9) * SQP * 64 + (size_t)q0 * 64
                      + abrow * 64 + abcir * 8;   // + kt*SQP*64

  // K frag read offsets (A operand; row = li): swizzled to match staging
  int koff[4];
#pragma unroll
  for (int f = 0; f < 4; ++f)
    koff[f] = (16 * f + li) * 32 + ((lg ^ ((li >> 1) & 3)) * 8);
  // V frag read offsets (B operand)
  int voff[4];
#pragma unroll
  for (int u = 0; u < 4; ++u) {  // u = df*2+kk
    int df = u >> 1, kk = u & 1;
    voff[u] = (16 * df + li) * 64 + (((kk * 4 + lg) ^ (li & 7)) * 8);
  }
  // ab read offsets (bytes): row = 16*wv + li (block q-row!), cols 16f+4lg..+3
  int aboff[4];
#pragma unroll
  for (int f = 0; f < 4; ++f)
    aboff[f] = (16 * wv + li) * 128 + (((2 * f + (lg >> 1)) ^ (li & 7)) << 4) + 8 * (lg & 1);

  // ---- prologue: stage tile 0 into buf 0 ----
  gld16(ksrc + (size_t)krow * 3072, (u16*)k_lds[0] + tid * 8);
  gld16(vsrc, (u16*)v_lds[0] + tid * 8);
  gld16(absrc0, (u16*)ab_lds[0] + tid * 8);
  gld16(absrc0 + 2048, (u16*)ab_lds[0] + 2048 + tid * 8);

  f32x4 o_acc[2] = {};
  float l_run = 0.f;

#pragma unroll 1
  for (int kt = 0; kt < 9; ++kt) {
    int cur = kt & 1;
    __syncthreads();  // stage(kt) landed; prev readers done
    if (kt < 8) {     // stage tile kt+1 -> other buffer; flies under this tile's compute
      int s = (kt + 1) * 64 + krow; if (s > 512) s = 512;
      gld16(ksrc + (size_t)s * 3072, (u16*)k_lds[cur ^ 1] + tid * 8);
      gld16(vsrc + (size_t)(kt + 1) * 64, (u16*)v_lds[cur ^ 1] + tid * 8);
      const u16* abn = absrc0 + (size_t)(kt + 1) * SQP * 64;
      gld16(abn, (u16*)ab_lds[cur ^ 1] + tid * 8);
      gld16(abn + 2048, (u16*)ab_lds[cur ^ 1] + 2048 + tid * 8);
    }
    const u16* kbp = k_lds[cur];
    const u16* vbf = v_lds[cur];
    const char* abl = (const char*)ab_lds[cur];

    // QK^T swapped: D[k-local][q]
    f32x4 sc[4];
    __builtin_amdgcn_s_setprio(1);
#pragma unroll
    for (int f = 0; f < 4; ++f) {
      short8 kf = *(const short8*)&kbp[koff[f]];
      f32x4 z = {};
      sc[f] = __builtin_amdgcn_mfma_f32_16x16x32_bf16(kf, qfrag, z, 0, 0, 0);
    }
    __builtin_amdgcn_s_setprio(0);

    // add ab (fp16 from LDS, 4 consecutive k per lane), exp, accumulate l, pack P
#pragma unroll
    for (int f = 0; f < 4; ++f) {
      uint2 uu = *(const uint2*)(abl + aboff[f]);
      float a0 = h2f((u16)(uu.x & 0xffffu));
      float a1 = h2f((u16)(uu.x >> 16));
      float a2 = h2f((u16)(uu.y & 0xffffu));
      float a3 = h2f((u16)(uu.y >> 16));
      float p0 = __expf(sc[f][0] + a0);
      float p1 = __expf(sc[f][1] + a1);
      float p2 = __expf(sc[f][2] + a2);
      float p3 = __expf(sc[f][3] + a3);
      l_run += (p0 + p1) + (p2 + p3);
      uint2 pk;
      pk.x = (u32)f2bf(p0) | ((u32)f2bf(p1) << 16);
      pk.y = (u32)f2bf(p2) | ((u32)f2bf(p3) << 16);
      *(uint2*)((char*)&p_lds[wv][0][0] + li * 144 + f * 32 + lg * 8) = pk;
    }

    // PV: out[16 q][32 d] += P[16][64] @ V[64][32]  (p_lds per-wave: no barrier)
    __builtin_amdgcn_s_setprio(1);
#pragma unroll
    for (int kk = 0; kk < 2; ++kk) {
      short8 pa = *(const short8*)&p_lds[wv][li][kk * 32 + lg * 8];
#pragma unroll
      for (int df = 0; df < 2; ++df) {
        short8 vb = *(const short8*)&vbf[voff[df * 2 + kk]];
        o_acc[df] = __builtin_amdgcn_mfma_f32_16x16x32_bf16(pa, vb, o_acc[df], 0, 0, 0);
      }
    }
    __builtin_amdgcn_s_setprio(0);
  }

  // ---- epilogue: reduce l over the 4 lg copies (q = li), redistribute, store ----
  float s = l_run;
  s += __shfl_xor(s, 16, 64);
  s += __shfl_xor(s, 32, 64);
  if (l < 16) l_lds[wv][l] = s;
  float lr[4];
#pragma unroll
  for (int r = 0; r < 4; ++r) lr[r] = l_lds[wv][4 * lg + r];
#pragma unroll
  for (int df = 0; df < 2; ++df)
#pragma unroll
    for (int r = 0; r < 4; ++r) {
      int s_q = sqb + r;
      if (s_q <= 512)
        o[(size_t)(b * SQ + s_q) * 1024 + h * DKH + 16 * df + li] = f2bf(o_acc[df][r] / lr[r]);
    }
}

extern "C" void kernel_launch(void* const* d_in, const int* in_sizes, int n_in,
                              void* d_out, int out_size, void* d_ws, size_t ws_size,
                              hipStream_t stream) {
  const float* x        = (const float*)d_in[0];
  const float* attn_bias= (const float*)d_in[1];
  const float* rel_emb  = (const float*)d_in[2];
  const float* Wq = (const float*)d_in[3];
  const float* bq = (const float*)d_in[4];
  const float* Wk = (const float*)d_in[5];
  const float* bk = (const float*)d_in[6];
  const float* Wv = (const float*)d_in[7];
  const float* bv = (const float*)d_in[8];
  const float* Wo = (const float*)d_in[9];
  const float* bo = (const float*)d_in[10];
  const float* W1 = (const float*)d_in[11];
  const float* b1 = (const float*)d_in[12];
  const float* W2 = (const float*)d_in[13];
  const float* b2 = (const float*)d_in[14];
  const float* ln1g = (const float*)d_in[15];
  const float* ln1b = (const float*)d_in[16];
  const float* ln2g = (const float*)d_in[17];
  const float* ln2b = (const float*)d_in[18];
  const int*   rel_pos = (const int*)d_in[19];
  float* out = (float*)d_out;

  char* ws = (char*)d_ws;
  size_t off = 0;
  auto alloc = [&](size_t bytes) { char* p = ws + off; off += (bytes + 255) & ~(size_t)255; return p; };
  u16* w_qkvT = (u16*)alloc((size_t)3072 * 1024 * 2);
  u16* w_oT   = (u16*)alloc((size_t)1024 * 1024 * 2);
  u16* w_1T   = (u16*)alloc((size_t)4096 * 1024 * 2);
  u16* w_2T   = (u16*)alloc((size_t)1024 * 4096 * 2);
  float* bias_qkv = (float*)alloc(3072 * 4);
  u16* ybuf = (u16*)alloc((size_t)MPAD * 1024 * 2);   // y1, later y2
  u16* obuf = (u16*)alloc((size_t)MPAD * 1024 * 2);   // attention output
  u16* vTb  = (u16*)alloc((size_t)8 * NHEADS * DKH * SVP * 2);  // V^T [b][h][d][SVP]
  u16* big  = (u16*)alloc((size_t)MPAD * 4096 * 2);   // qkv [MPAD][3072], later ffn1 [MPAD][4096]
  float* part = (float*)alloc((size_t)2 * MPAD * 1024 * 4);     // split-K partials (O-proj, FFN2)
  u16* abt  = (u16*)alloc((size_t)256 * 9 * SQP * 64 * 2);      // baked bias tiles (fp16), 170 MB

  const float scale = 0.17677669529663689f;  // 32^-0.5
  dim3 blk(256);

  prep_ab<<<dim3(256, 36), blk, 0, stream>>>(attn_bias, rel_pos, rel_emb, abt);
  transpose_cast_k<<<dim3(32, 32), blk, 0, stream>>>(Wq, w_qkvT, 1024, 1024, scale);
  transpose_cast_k<<<dim3(32, 32), blk, 0, stream>>>(Wk, w_qkvT + (size_t)1024 * 1024, 1024, 1024, 1.f);
  transpose_cast_k<<<dim3(32, 32), blk, 0, stream>>>(Wv, w_qkvT + (size_t)2048 * 1024, 1024, 1024, 1.f);
  transpose_cast_k<<<dim3(32, 32), blk, 0, stream>>>(Wo, w_oT, 1024, 1024, 1.f);
  transpose_cast_k<<<dim3(128, 32), blk, 0, stream>>>(W1, w_1T, 1024, 4096, 1.f);
  transpose_cast_k<<<dim3(32, 128), blk, 0, stream>>>(W2, w_2T, 4096, 1024, 1.f);
  prep_bias_k<<<12, blk, 0, stream>>>(bq, bk, bv, bias_qkv, scale);

  ln_k<<<MV, blk, 0, stream>>>(x, ln1g, ln1b, ybuf);
  gemm_bt<0><<<33 * 24, blk, 0, stream>>>(ybuf, w_qkvT, bias_qkv, nullptr, big, 3072, 1024, 24);
  vtrans_k<<<dim3(18, NHEADS, 8), blk, 0, stream>>>(big, vTb);
  attn_fused<<<8 * NHEADS * 9, blk, 0, stream>>>(big, vTb, abt, obuf);
  gemm_bt<4><<<33 * 8 * 2, blk, 0, stream>>>(obuf, w_oT, bo, nullptr, part, 1024, 1024, 8);
  oproj_combine<<<MV, blk, 0, stream>>>(part, out, bo, x);
  ln_k<<<MV, blk, 0, stream>>>(out, ln2g, ln2b, ybuf);
  gemm_bt<2><<<33 * 32, blk, 0, stream>>>(ybuf, w_1T, b1, nullptr, big, 4096, 1024, 32);
  gemm_bt<4><<<33 * 8 * 2, blk, 0, stream>>>(big, w_2T, b2, nullptr, part, 1024, 4096, 8);
  ffn2_combine<<<MV, blk, 0, stream>>>(part, out, b2);
}

// Round 14
// 548.925 us; speedup vs baseline: 1.1025x; 1.1025x over previous
//
#include <hip/hip_runtime.h>
#include <hip/hip_bf16.h>
#include <math.h>

typedef __attribute__((ext_vector_type(8))) short short8;
typedef __attribute__((ext_vector_type(4))) float f32x4;
typedef unsigned short u16;
typedef unsigned int u32;

#define SQ 513
#define MPAD 4224
#define MV 4104
#define NHEADS 32
#define DKH 32
#define SVP 576   // padded s extent for vT
#define SQP 576   // padded q extent for ab tiles

// round-to-nearest-even f32 -> bf16 (as u16 bits)
static __device__ inline u16 f2bf(float f) {
  u32 u = __builtin_bit_cast(u32, f);
  u = (u + 0x7fffu + ((u >> 16) & 1u)) >> 16;
  return (u16)u;
}

// f32 -> fp16 bits (RTE)
static __device__ inline u16 f2h(float f) {
  _Float16 h = (_Float16)f;
  return __builtin_bit_cast(u16, h);
}
static __device__ inline float h2f(u16 b) {
  return (float)__builtin_bit_cast(_Float16, b);
}

static __device__ inline void gld16(const void* g, void* l) {
  __builtin_amdgcn_global_load_lds((__attribute__((address_space(1))) void*)g,
                                   (__attribute__((address_space(3))) void*)l,
                                   16, 0, 0);
}

static __device__ inline float gelu_f(float x) {
  return 0.5f * x * (1.f + erff(x * 0.70710678118654752f));
}

// ---------------- weight transpose + cast: in f32 [K][N] -> out bf16 [N][K] ----------------
__global__ __launch_bounds__(256) void transpose_cast_k(const float* __restrict__ in,
    u16* __restrict__ out, int K, int N, float scale)
{
  __shared__ float t[32][33];
  int n0 = blockIdx.x * 32, k0 = blockIdx.y * 32;
  int tx = threadIdx.x & 31, ty = threadIdx.x >> 5;
#pragma unroll
  for (int i = 0; i < 32; i += 8)
    t[ty + i][tx] = in[(size_t)(k0 + ty + i) * N + n0 + tx];
  __syncthreads();
#pragma unroll
  for (int i = 0; i < 32; i += 8)
    out[(size_t)(n0 + ty + i) * K + k0 + tx] = f2bf(t[tx][ty + i] * scale);
}

// ---------------- V transpose: qkv V-region -> vT[b][h][d][SVP] (bf16) ----------------
__global__ __launch_bounds__(256) void vtrans_k(const u16* __restrict__ qkv,
    u16* __restrict__ vT)
{
  __shared__ u16 t[32][33];
  int st = blockIdx.x * 32, h = blockIdx.y, b = blockIdx.z;
  int tx = threadIdx.x & 31, ty = threadIdx.x >> 5;
#pragma unroll
  for (int i = 0; i < 32; i += 8) {
    int s = st + ty + i;
    int sc = s > 512 ? 512 : s;  // clamp: pad region gets finite data
    t[ty + i][tx] = qkv[(size_t)(b * SQ + sc) * 3072 + 2048 + h * DKH + tx];
  }
  __syncthreads();
#pragma unroll
  for (int i = 0; i < 32; i += 8) {
    int d = ty + i;
    vT[(((size_t)b * NHEADS + h) * DKH + d) * SVP + st + tx] = t[tx][d];
  }
}

// ---------------- prep_ab: bake bias+relpos+mask into tiled fp16 abt[bh][9][SQP][64] ----------------
// grid (256 bh, 36 sq-chunks of 16). rel_pos values are in [0,16) for this problem, so the
// rel_emb slice per head is 16 floats: loaded once into lanes 0..15 and gathered via __shfl
// (LDS pipe) instead of a per-element global scatter-gather — R13's prep_ab was TA-bound on
// that gather (1.35 TB/s, VALU 11%, occupancy 87%: memory-pipe transaction serialization).
// Edge masking baked in: sq>512 or sk>512 -> -30000 (fp16-safe; exp(s-30000)=0);
// sq==0 or sk==0 -> base; else masked inner.
__global__ __launch_bounds__(256) void prep_ab(const float* __restrict__ attn_bias,
    const int* __restrict__ rel_pos, const float* __restrict__ rel_emb,
    u16* __restrict__ abt)
{
  int bh = blockIdx.x;
  int b = bh >> 5, h = bh & 31;
  int t = threadIdx.x;
  float tv = rel_emb[(size_t)(t & 15) * NHEADS + h];  // lanes 0..15: rel_emb rows 0..15
  const float* brow_base = attn_bias + ((size_t)bh * SQ) * SQ;
#pragma unroll 1
  for (int rl = 0; rl < 16; ++rl) {
    int sq = blockIdx.y * 16 + rl;
#pragma unroll
    for (int cc = 0; cc < 3; ++cc) {
      int sk = t + cc * 256;          // 0..767
      if (sk >= SQP) continue;        // cc==2: only t<64 participate
      float ab;
      if (sq > 512 || sk > 512) ab = -30000.f;
      else {
        float base = brow_base[(size_t)sq * SQ + sk];
        if (sq == 0 || sk == 0) ab = base;
        else {
          int rp = rel_pos[((size_t)b * 512 + sq - 1) * 512 + sk - 1];
          float re = __shfl(tv, rp & 15, 64);
          float inner = base + re;
          ab = (rp <= 15 || inner < -1e8f) ? inner : 0.f;
          if (ab < -30000.f) ab = -30000.f;
        }
      }
      int kt = sk >> 6, kp = sk & 63;
      abt[(((size_t)bh * 9 + kt) * SQP + sq) * 64 + kp] = f2h(ab);
    }
  }
}

// ---------------- concat qkv bias (scale on bq) ----------------
__global__ __launch_bounds__(256) void prep_bias_k(const float* __restrict__ bq,
    const float* __restrict__ bk, const float* __restrict__ bv,
    float* __restrict__ out, float scale)
{
  int i = blockIdx.x * 256 + threadIdx.x;
  float v = (i < 1024) ? bq[i] * scale : ((i < 2048) ? bk[i - 1024] : bv[i - 2048]);
  out[i] = v;
}

// ---------------- layernorm: f32 [rows][1024] -> bf16 ----------------
__global__ __launch_bounds__(256) void ln_k(const float* __restrict__ in,
    const float* __restrict__ g, const float* __restrict__ b,
    u16* __restrict__ out)
{
  int row = blockIdx.x;
  float4 v = ((const float4*)(in + (size_t)row * 1024))[threadIdx.x];
  float s = v.x + v.y + v.z + v.w;
  float s2 = v.x * v.x + v.y * v.y + v.z * v.z + v.w * v.w;
#pragma unroll
  for (int d = 32; d; d >>= 1) { s += __shfl_xor(s, d, 64); s2 += __shfl_xor(s2, d, 64); }
  __shared__ float ps[4], ps2[4];
  int w = threadIdx.x >> 6;
  if ((threadIdx.x & 63) == 0) { ps[w] = s; ps2[w] = s2; }
  __syncthreads();
  s = ps[0] + ps[1] + ps[2] + ps[3];
  s2 = ps2[0] + ps2[1] + ps2[2] + ps2[3];
  float mean = s * (1.f / 1024.f);
  float var = s2 * (1.f / 1024.f) - mean * mean;
  float inv = rsqrtf(var + 1e-5f);
  float4 gv = ((const float4*)g)[threadIdx.x];
  float4 bv = ((const float4*)b)[threadIdx.x];
  ushort4 o;
  o.x = f2bf((v.x - mean) * inv * gv.x + bv.x);
  o.y = f2bf((v.y - mean) * inv * gv.y + bv.y);
  o.z = f2bf((v.z - mean) * inv * gv.z + bv.z);
  o.w = f2bf((v.w - mean) * inv * gv.w + bv.w);
  ((ushort4*)(out + (size_t)row * 1024))[threadIdx.x] = o;
}

// ---------------- bf16 GEMM: C[M][N] = A[M][K] @ Bw[N][K]^T + bias, epilogues ----------------
// EPI 0: bf16 store (all padded rows)        [QKV]
// EPI 2: gelu, bf16 store                    [FFN1]
// EPI 4: split-K=2 partial f32 store         [O-proj / FFN2 halves]
template <int EPI>
__global__ __launch_bounds__(256) void gemm_bt(const u16* __restrict__ A,
    const u16* __restrict__ Bw, const float* __restrict__ bias,
    const float* __restrict__ resid, void* __restrict__ outp,
    int N, int K, int nbx)
{
  __shared__ alignas(16) u16 sA[128 * 64];
  __shared__ alignas(16) u16 sB[128 * 64];
  int tid = threadIdx.x;
  int l = tid & 63, lg = l >> 4, li = l & 15;

  int bidx = blockIdx.x;
  int kbeg = 0, kend = K;
  float* pout = (float*)outp;
  if (EPI == 4) {
    int half = gridDim.x >> 1;
    int s = bidx >= half;
    bidx -= s * half;
    kbeg = s * (K >> 1);
    kend = kbeg + (K >> 1);
    pout += (size_t)s * MPAD * 1024;
  }
  int mb = bidx / nbx, nb = bidx % nbx;
  int m0 = mb * 128, n0 = nb * 128;
  int wv = tid >> 6;
  int wr = wv >> 1, wc = wv & 1;
  f32x4 acc[4][4] = {};
  int r_ = tid >> 3, c_ = (tid & 7) * 8;
  const u16* Ag = A + (size_t)(m0 + r_) * K + c_;
  const u16* Bg = Bw + (size_t)(n0 + r_) * K + c_;
  u16* sAb = sA + (tid & 192) * 8;   // wave-uniform staging base
  u16* sBb = sB + (tid & 192) * 8;

  for (int k0 = kbeg; k0 < kend; k0 += 64) {
    __syncthreads();
#pragma unroll
    for (int i = 0; i < 4; ++i) {
      gld16(Ag + (size_t)(i * 32) * K + k0, sAb + i * 2048);
      gld16(Bg + (size_t)(i * 32) * K + k0, sBb + i * 2048);
    }
    __syncthreads();
#pragma unroll
    for (int ks = 0; ks < 2; ++ks) {
      short8 af[4], bfr[4];
#pragma unroll
      for (int i = 0; i < 4; ++i)
        af[i] = *(const short8*)&sA[(64 * wr + 16 * i + li) * 64 + ks * 32 + lg * 8];
#pragma unroll
      for (int j = 0; j < 4; ++j)
        bfr[j] = *(const short8*)&sB[(64 * wc + 16 * j + li) * 64 + ks * 32 + lg * 8];
#pragma unroll
      for (int i = 0; i < 4; ++i)
#pragma unroll
        for (int j = 0; j < 4; ++j)
          acc[i][j] = __builtin_amdgcn_mfma_f32_16x16x32_bf16(af[i], bfr[j], acc[i][j], 0, 0, 0);
    }
  }

#pragma unroll
  for (int i = 0; i < 4; ++i) {
    int rb = m0 + 64 * wr + 16 * i + 4 * lg;
#pragma unroll
    for (int j = 0; j < 4; ++j) {
      int col = n0 + 64 * wc + 16 * j + li;
      float bia = (EPI == 4) ? 0.f : bias[col];
#pragma unroll
      for (int r = 0; r < 4; ++r) {
        int row = rb + r;
        float v = acc[i][j][r] + bia;
        if (EPI == 0) {
          ((u16*)outp)[(size_t)row * N + col] = f2bf(v);
        } else if (EPI == 2) {
          ((u16*)outp)[(size_t)row * N + col] = f2bf(gelu_f(v));
        } else {
          pout[(size_t)row * N + col] = v;
        }
      }
    }
  }
}

// ---------------- combine kernels ----------------
// O-proj: out = p0 + p1 + bo + x   (grid MV x 256)
__global__ __launch_bounds__(256) void oproj_combine(const float* __restrict__ part,
    float* __restrict__ out, const float* __restrict__ bo, const float* __restrict__ x)
{
  size_t idx = (size_t)blockIdx.x * 256 + threadIdx.x;
  const float4* p0 = (const float4*)part;
  const float4* p1 = (const float4*)(part + (size_t)MPAD * 1024);
  float4 a = p0[idx], b = p1[idx];
  float4 bb = ((const float4*)bo)[idx & 255];
  float4 xx = ((const float4*)x)[idx];
  a.x += b.x + bb.x + xx.x;
  a.y += b.y + bb.y + xx.y;
  a.z += b.z + bb.z + xx.z;
  a.w += b.w + bb.w + xx.w;
  ((float4*)out)[idx] = a;
}

// FFN2: out += p0 + p1 + b2   (grid MV x 256)
__global__ __launch_bounds__(256) void ffn2_combine(const float* __restrict__ part,
    float* __restrict__ out, const float* __restrict__ b2)
{
  size_t idx = (size_t)blockIdx.x * 256 + threadIdx.x;
  const float4* p0 = (const float4*)part;
  const float4* p1 = (const float4*)(part + (size_t)MPAD * 1024);
  float4 a = ((float4*)out)[idx];
  float4 x0 = p0[idx], x1 = p1[idx];
  float4 bb = ((const float4*)b2)[idx & 255];
  a.x += x0.x + x1.x + bb.x;
  a.y += x0.y + x1.y + bb.y;
  a.z += x0.z + x1.z + bb.z;
  a.w += x0.w + x1.w + bb.w;
  ((float4*)out)[idx] = a;
}

// ---------------- fused flash attention (precomputed fp16 ab tiles, swapped QK^T) ----------------
// grid: (b, h, qtile of 64); block 256 = 4 waves; each wave owns 16 q-rows.
// All bias/relpos/mask logic pre-baked into abt (fp16 tiles); per k-tile the 8-KB ab tile
// is staged into LDS via global_load_lds (contiguous stream) alongside K and V^T.
// QK^T computed SWAPPED: sc[f] = mfma(K, Q) -> D[row=k-local=16f+4lg+r][col=q=li], so a
// lane's 4 ab values are k-consecutive -> one 8B LDS read per f. ab LDS row is the
// block q-row (16*wv + li) — the R11/R12 bug.
__global__ __launch_bounds__(256) void attn_fused(const u16* __restrict__ qkv,
    const u16* __restrict__ vT, const u16* __restrict__ abt,
    u16* __restrict__ o)
{
  __shared__ alignas(16) u16 k_lds[2][64 * 32];
  __shared__ alignas(16) u16 v_lds[2][32 * 64];
  __shared__ alignas(16) u16 ab_lds[2][64 * 64];
  __shared__ alignas(16) u16 p_lds[4][16][72];
  __shared__ float l_lds[4][16];
  int bid = blockIdx.x;
  int qt = bid % 9, h = (bid / 9) % NHEADS, b = bid / (9 * NHEADS);
  int tid = threadIdx.x, wv = tid >> 6, l = tid & 63, lg = l >> 4, li = l & 15;
  int q0 = qt * 64;
  int sqb = q0 + 16 * wv + 4 * lg;

  // Q fragment (B operand now; same register layout): col = li (q), k(d) = lg*8+e
  short8 qfrag = *(const short8*)(qkv + (size_t)(b * SQ + q0 + 16 * wv + li) * 3072 + h * DKH + lg * 8);

  // --- staging coords (global_load_lds: dest = lds_base + tid*16B, linear) ---
  int krow = tid >> 2;
  int kchunk = (tid & 3) ^ ((tid >> 3) & 3);
  const u16* ksrc = qkv + (size_t)(b * SQ) * 3072 + 1024 + h * DKH + kchunk * 8;  // + s*3072
  int vrow = tid >> 3;
  int vchunk = (tid & 7) ^ (vrow & 7);
  const u16* vsrc = vT + (((size_t)b * NHEADS + h) * DKH + vrow) * SVP + vchunk * 8;  // + kt*64
  // ab tile: 512 chunks; thread stages dest chunks tid and tid+256; read-side XOR swizzle
  // (chunk-in-row ^ (row&7)) -> source pre-swizzled; second round = +32 rows (row&7 invariant).
  int abrow = tid >> 3;
  int abcir = (tid & 7) ^ (abrow & 7);
  const u16* absrc0 = abt + ((size_t)(b * NHEADS + h) * 9) * SQP * 64 + (size_t)q0 * 64
                      + abrow * 64 + abcir * 8;   // + kt*SQP*64

  // K frag read offsets (A operand; row = li): swizzled to match staging
  int koff[4];
#pragma unroll
  for (int f = 0; f < 4; ++f)
    koff[f] = (16 * f + li) * 32 + ((lg ^ ((li >> 1) & 3)) * 8);
  // V frag read offsets (B operand)
  int voff[4];
#pragma unroll
  for (int u = 0; u < 4; ++u) {  // u = df*2+kk
    int df = u >> 1, kk = u & 1;
    voff[u] = (16 * df + li) * 64 + (((kk * 4 + lg) ^ (li & 7)) * 8);
  }
  // ab read offsets (bytes): row = 16*wv + li (block q-row), cols 16f+4lg..+3
  int aboff[4];
#pragma unroll
  for (int f = 0; f < 4; ++f)
    aboff[f] = (16 * wv + li) * 128 + (((2 * f + (lg >> 1)) ^ (li & 7)) << 4) + 8 * (lg & 1);

  // ---- prologue: stage tile 0 into buf 0 ----
  gld16(ksrc + (size_t)krow * 3072, (u16*)k_lds[0] + tid * 8);
  gld16(vsrc, (u16*)v_lds[0] + tid * 8);
  gld16(absrc0, (u16*)ab_lds[0] + tid * 8);
  gld16(absrc0 + 2048, (u16*)ab_lds[0] + 2048 + tid * 8);

  f32x4 o_acc[2] = {};
  float l_run = 0.f;

#pragma unroll 1
  for (int kt = 0; kt < 9; ++kt) {
    int cur = kt & 1;
    __syncthreads();  // stage(kt) landed; prev readers done
    if (kt < 8) {     // stage tile kt+1 -> other buffer; flies under this tile's compute
      int s = (kt + 1) * 64 + krow; if (s > 512) s = 512;
      gld16(ksrc + (size_t)s * 3072, (u16*)k_lds[cur ^ 1] + tid * 8);
      gld16(vsrc + (size_t)(kt + 1) * 64, (u16*)v_lds[cur ^ 1] + tid * 8);
      const u16* abn = absrc0 + (size_t)(kt + 1) * SQP * 64;
      gld16(abn, (u16*)ab_lds[cur ^ 1] + tid * 8);
      gld16(abn + 2048, (u16*)ab_lds[cur ^ 1] + 2048 + tid * 8);
    }
    const u16* kbp = k_lds[cur];
    const u16* vbf = v_lds[cur];
    const char* abl = (const char*)ab_lds[cur];

    // QK^T swapped: D[k-local][q]
    f32x4 sc[4];
    __builtin_amdgcn_s_setprio(1);
#pragma unroll
    for (int f = 0; f < 4; ++f) {
      short8 kf = *(const short8*)&kbp[koff[f]];
      f32x4 z = {};
      sc[f] = __builtin_amdgcn_mfma_f32_16x16x32_bf16(kf, qfrag, z, 0, 0, 0);
    }
    __builtin_amdgcn_s_setprio(0);

    // add ab (fp16 from LDS, 4 consecutive k per lane), exp, accumulate l, pack P
#pragma unroll
    for (int f = 0; f < 4; ++f) {
      uint2 uu = *(const uint2*)(abl + aboff[f]);
      float a0 = h2f((u16)(uu.x & 0xffffu));
      float a1 = h2f((u16)(uu.x >> 16));
      float a2 = h2f((u16)(uu.y & 0xffffu));
      float a3 = h2f((u16)(uu.y >> 16));
      float p0 = __expf(sc[f][0] + a0);
      float p1 = __expf(sc[f][1] + a1);
      float p2 = __expf(sc[f][2] + a2);
      float p3 = __expf(sc[f][3] + a3);
      l_run += (p0 + p1) + (p2 + p3);
      uint2 pk;
      pk.x = (u32)f2bf(p0) | ((u32)f2bf(p1) << 16);
      pk.y = (u32)f2bf(p2) | ((u32)f2bf(p3) << 16);
      *(uint2*)((char*)&p_lds[wv][0][0] + li * 144 + f * 32 + lg * 8) = pk;
    }

    // PV: out[16 q][32 d] += P[16][64] @ V[64][32]  (p_lds per-wave: no barrier)
    __builtin_amdgcn_s_setprio(1);
#pragma unroll
    for (int kk = 0; kk < 2; ++kk) {
      short8 pa = *(const short8*)&p_lds[wv][li][kk * 32 + lg * 8];
#pragma unroll
      for (int df = 0; df < 2; ++df) {
        short8 vb = *(const short8*)&vbf[voff[df * 2 + kk]];
        o_acc[df] = __builtin_amdgcn_mfma_f32_16x16x32_bf16(pa, vb, o_acc[df], 0, 0, 0);
      }
    }
    __builtin_amdgcn_s_setprio(0);
  }

  // ---- epilogue: reduce l over the 4 lg copies (q = li), redistribute, store ----
  float s = l_run;
  s += __shfl_xor(s, 16, 64);
  s += __shfl_xor(s, 32, 64);
  if (l < 16) l_lds[wv][l] = s;
  float lr[4];
#pragma unroll
  for (int r = 0; r < 4; ++r) lr[r] = l_lds[wv][4 * lg + r];
#pragma unroll
  for (int df = 0; df < 2; ++df)
#pragma unroll
    for (int r = 0; r < 4; ++r) {
      int s_q = sqb + r;
      if (s_q <= 512)
        o[(size_t)(b * SQ + s_q) * 1024 + h * DKH + 16 * df + li] = f2bf(o_acc[df][r] / lr[r]);
    }
}

extern "C" void kernel_launch(void* const* d_in, const int* in_sizes, int n_in,
                              void* d_out, int out_size, void* d_ws, size_t ws_size,
                              hipStream_t stream) {
  const float* x        = (const float*)d_in[0];
  const float* attn_bias= (const float*)d_in[1];
  const float* rel_emb  = (const float*)d_in[2];
  const float* Wq = (const float*)d_in[3];
  const float* bq = (const float*)d_in[4];
  const float* Wk = (const float*)d_in[5];
  const float* bk = (const float*)d_in[6];
  const float* Wv = (const float*)d_in[7];
  const float* bv = (const float*)d_in[8];
  const float* Wo = (const float*)d_in[9];
  const float* bo = (const float*)d_in[10];
  const float* W1 = (const float*)d_in[11];
  const float* b1 = (const float*)d_in[12];
  const float* W2 = (const float*)d_in[13];
  const float* b2 = (const float*)d_in[14];
  const float* ln1g = (const float*)d_in[15];
  const float* ln1b = (const float*)d_in[16];
  const float* ln2g = (const float*)d_in[17];
  const float* ln2b = (const float*)d_in[18];
  const int*   rel_pos = (const int*)d_in[19];
  float* out = (float*)d_out;

  char* ws = (char*)d_ws;
  size_t off = 0;
  auto alloc = [&](size_t bytes) { char* p = ws + off; off += (bytes + 255) & ~(size_t)255; return p; };
  u16* w_qkvT = (u16*)alloc((size_t)3072 * 1024 * 2);
  u16* w_oT   = (u16*)alloc((size_t)1024 * 1024 * 2);
  u16* w_1T   = (u16*)alloc((size_t)4096 * 1024 * 2);
  u16* w_2T   = (u16*)alloc((size_t)1024 * 4096 * 2);
  float* bias_qkv = (float*)alloc(3072 * 4);
  u16* ybuf = (u16*)alloc((size_t)MPAD * 1024 * 2);   // y1, later y2
  u16* obuf = (u16*)alloc((size_t)MPAD * 1024 * 2);   // attention output
  u16* vTb  = (u16*)alloc((size_t)8 * NHEADS * DKH * SVP * 2);  // V^T [b][h][d][SVP]
  u16* big  = (u16*)alloc((size_t)MPAD * 4096 * 2);   // qkv [MPAD][3072], later ffn1 [MPAD][4096]
  float* part = (float*)alloc((size_t)2 * MPAD * 1024 * 4);     // split-K partials (O-proj, FFN2)
  u16* abt  = (u16*)alloc((size_t)256 * 9 * SQP * 64 * 2);      // baked bias tiles (fp16), 170 MB

  const float scale = 0.17677669529663689f;  // 32^-0.5
  dim3 blk(256);

  prep_ab<<<dim3(256, 36), blk, 0, stream>>>(attn_bias, rel_pos, rel_emb, abt);
  transpose_cast_k<<<dim3(32, 32), blk, 0, stream>>>(Wq, w_qkvT, 1024, 1024, scale);
  transpose_cast_k<<<dim3(32, 32), blk, 0, stream>>>(Wk, w_qkvT + (size_t)1024 * 1024, 1024, 1024, 1.f);
  transpose_cast_k<<<dim3(32, 32), blk, 0, stream>>>(Wv, w_qkvT + (size_t)2048 * 1024, 1024, 1024, 1.f);
  transpose_cast_k<<<dim3(32, 32), blk, 0, stream>>>(Wo, w_oT, 1024, 1024, 1.f);
  transpose_cast_k<<<dim3(128, 32), blk, 0, stream>>>(W1, w_1T, 1024, 4096, 1.f);
  transpose_cast_k<<<dim3(32, 128), blk, 0, stream>>>(W2, w_2T, 4096, 1024, 1.f);
  prep_bias_k<<<12, blk, 0, stream>>>(bq, bk, bv, bias_qkv, scale);

  ln_k<<<MV, blk, 0, stream>>>(x, ln1g, ln1b, ybuf);
  gemm_bt<0><<<33 * 24, blk, 0, stream>>>(ybuf, w_qkvT, bias_qkv, nullptr, big, 3072, 1024, 24);
  vtrans_k<<<dim3(18, NHEADS, 8), blk, 0, stream>>>(big, vTb);
  attn_fused<<<8 * NHEADS * 9, blk, 0, stream>>>(big, vTb, abt, obuf);
  gemm_bt<4><<<33 * 8 * 2, blk, 0, stream>>>(obuf, w_oT, bo, nullptr, part, 1024, 1024, 8);
  oproj_combine<<<MV, blk, 0, stream>>>(part, out, bo, x);
  ln_k<<<MV, blk, 0, stream>>>(out, ln2g, ln2b, ybuf);
  gemm_bt<2><<<33 * 32, blk, 0, stream>>>(ybuf, w_1T, b1, nullptr, big, 4096, 1024, 32);
  gemm_bt<4><<<33 * 8 * 2, blk, 0, stream>>>(big, w_2T, b2, nullptr, part, 1024, 4096, 8);
  ffn2_combine<<<MV, blk, 0, stream>>>(part, out, b2);
}

// Round 15
// 516.814 us; speedup vs baseline: 1.1710x; 1.0621x over previous
//
#include <hip/hip_runtime.h>
#include <hip/hip_bf16.h>
#include <math.h>

typedef __attribute__((ext_vector_type(8))) short short8;
typedef __attribute__((ext_vector_type(4))) float f32x4;
typedef unsigned short u16;
typedef unsigned int u32;

#define SQ 513
#define MPAD 4224
#define MV 4104
#define NHEADS 32
#define DKH 32
#define SVP 576   // padded s extent for vT
#define SQP 576   // padded q extent for ab tiles

// round-to-nearest-even f32 -> bf16 (as u16 bits)
static __device__ inline u16 f2bf(float f) {
  u32 u = __builtin_bit_cast(u32, f);
  u = (u + 0x7fffu + ((u >> 16) & 1u)) >> 16;
  return (u16)u;
}

// f32 -> fp16 bits (RTE)
static __device__ inline u16 f2h(float f) {
  _Float16 h = (_Float16)f;
  return __builtin_bit_cast(u16, h);
}
static __device__ inline float h2f(u16 b) {
  return (float)__builtin_bit_cast(_Float16, b);
}

static __device__ inline void gld16(const void* g, void* l) {
  __builtin_amdgcn_global_load_lds((__attribute__((address_space(1))) void*)g,
                                   (__attribute__((address_space(3))) void*)l,
                                   16, 0, 0);
}

static __device__ inline float gelu_f(float x) {
  return 0.5f * x * (1.f + erff(x * 0.70710678118654752f));
}

// ---------------- weight transpose + cast: in f32 [K][N] -> out bf16 [N][K] ----------------
__global__ __launch_bounds__(256) void transpose_cast_k(const float* __restrict__ in,
    u16* __restrict__ out, int K, int N, float scale)
{
  __shared__ float t[32][33];
  int n0 = blockIdx.x * 32, k0 = blockIdx.y * 32;
  int tx = threadIdx.x & 31, ty = threadIdx.x >> 5;
#pragma unroll
  for (int i = 0; i < 32; i += 8)
    t[ty + i][tx] = in[(size_t)(k0 + ty + i) * N + n0 + tx];
  __syncthreads();
#pragma unroll
  for (int i = 0; i < 32; i += 8)
    out[(size_t)(n0 + ty + i) * K + k0 + tx] = f2bf(t[tx][ty + i] * scale);
}

// ---------------- V transpose: qkv V-region -> vT[b][h][d][SVP] (bf16) ----------------
__global__ __launch_bounds__(256) void vtrans_k(const u16* __restrict__ qkv,
    u16* __restrict__ vT)
{
  __shared__ u16 t[32][33];
  int st = blockIdx.x * 32, h = blockIdx.y, b = blockIdx.z;
  int tx = threadIdx.x & 31, ty = threadIdx.x >> 5;
#pragma unroll
  for (int i = 0; i < 32; i += 8) {
    int s = st + ty + i;
    int sc = s > 512 ? 512 : s;  // clamp: pad region gets finite data
    t[ty + i][tx] = qkv[(size_t)(b * SQ + sc) * 3072 + 2048 + h * DKH + tx];
  }
  __syncthreads();
#pragma unroll
  for (int i = 0; i < 32; i += 8) {
    int d = ty + i;
    vT[(((size_t)b * NHEADS + h) * DKH + d) * SVP + st + tx] = t[tx][d];
  }
}

// ---------------- prep_ab v2 (vectorized 4-wide): bake bias+relpos+mask -> fp16 abt[bh][9][SQP][64] ----
// grid (256 bh, 36 sq-chunks of 16). Thread tt<144 owns 4 consecutive sk: float4 bias +
// int4 rel_pos + ushort4 store (vmem inst count /4 vs R14 — R14 was vmem-issue/latency-bound
// at 1.9 TB/s, VALU 15%). rp[sk-1] comes from the previous lane's int4 .w via __shfl
// (lane l==0 scalar-loads it; tt==0 needs none: sk==0 takes the base path).
// sk==512 is a scalar special (float4 there would read past the buffer's last element).
// rel_emb gathered via lane-table __shfl (rp in [0,16)). Edge rules baked:
// sq>512 or sk>512 -> -30000 (fp16-safe; exp->0); sq==0 or sk==0 -> base; else masked inner.
__global__ __launch_bounds__(256) void prep_ab(const float* __restrict__ attn_bias,
    const int* __restrict__ rel_pos, const float* __restrict__ rel_emb,
    u16* __restrict__ abt)
{
  int bh = blockIdx.x;
  int b = bh >> 5, h = bh & 31;
  int t = threadIdx.x;
  int l = t & 63;
  float tv = rel_emb[(size_t)(l & 15) * NHEADS + h];  // lanes 0..15 hold rel_emb rows 0..15
  int tt = t;
  int sk = tt * 4;
  bool active = tt < 144;  // 144*4 = 576 = SQP
  int kt = sk >> 6, kp = sk & 63;
  const float* bbase = attn_bias + (size_t)bh * SQ * SQ;
  const int* rbase = rel_pos + (size_t)b * 512 * 512;

#pragma unroll 2
  for (int rl = 0; rl < 16; ++rl) {
    int sq = blockIdx.y * 16 + rl;
    int srow = sq > 512 ? 512 : sq;
    int sqm = sq - 1; sqm = sqm < 0 ? 0 : (sqm > 511 ? 511 : sqm);
    float4 bv = {0.f, 0.f, 0.f, 0.f};
    int4 rv = {0, 0, 0, 0};
    if (active) {
      if (sk <= 508) {
        bv = *(const float4*)(bbase + (size_t)srow * SQ + sk);
        rv = *(const int4*)(rbase + (size_t)sqm * 512 + sk);
      } else if (sk == 512) {
        bv.x = bbase[(size_t)srow * SQ + 512];
      }
    }
    // rp[sk-1]: previous lane's rv.w; wave-boundary / special lanes load scalar
    int pw = __shfl(rv.w, (l - 1) & 63, 64);
    if (active) {
      if (l == 0 && tt > 0 && sk <= 508) pw = rbase[(size_t)sqm * 512 + sk - 1];
      if (sk == 512) pw = rbase[(size_t)sqm * 512 + 511];
    }
    int rpj0 = pw, rpj1 = rv.x, rpj2 = rv.y, rpj3 = rv.z;
    float re0 = __shfl(tv, rpj0 & 15, 64);
    float re1 = __shfl(tv, rpj1 & 15, 64);
    float re2 = __shfl(tv, rpj2 & 15, 64);
    float re3 = __shfl(tv, rpj3 & 15, 64);
    ushort4 outv;
    {
      float bj[4] = {bv.x, bv.y, bv.z, bv.w};
      int rj[4] = {rpj0, rpj1, rpj2, rpj3};
      float rej[4] = {re0, re1, re2, re3};
      u16 op[4];
#pragma unroll
      for (int j = 0; j < 4; ++j) {
        int skj = sk + j;
        float abv;
        if (sq > 512 || skj > 512) abv = -30000.f;
        else {
          float base = bj[j];
          if (sq == 0 || skj == 0) abv = base;
          else {
            float inner = base + rej[j];
            abv = (rj[j] <= 15 || inner < -1e8f) ? inner : 0.f;
            if (abv < -30000.f) abv = -30000.f;
          }
        }
        op[j] = f2h(abv);
      }
      outv.x = op[0]; outv.y = op[1]; outv.z = op[2]; outv.w = op[3];
    }
    if (active)
      *(ushort4*)(abt + (((size_t)bh * 9 + kt) * SQP + sq) * 64 + kp) = outv;
  }
}

// ---------------- concat qkv bias (scale on bq) ----------------
__global__ __launch_bounds__(256) void prep_bias_k(const float* __restrict__ bq,
    const float* __restrict__ bk, const float* __restrict__ bv,
    float* __restrict__ out, float scale)
{
  int i = blockIdx.x * 256 + threadIdx.x;
  float v = (i < 1024) ? bq[i] * scale : ((i < 2048) ? bk[i - 1024] : bv[i - 2048]);
  out[i] = v;
}

// ---------------- layernorm: f32 [rows][1024] -> bf16 ----------------
__global__ __launch_bounds__(256) void ln_k(const float* __restrict__ in,
    const float* __restrict__ g, const float* __restrict__ b,
    u16* __restrict__ out)
{
  int row = blockIdx.x;
  float4 v = ((const float4*)(in + (size_t)row * 1024))[threadIdx.x];
  float s = v.x + v.y + v.z + v.w;
  float s2 = v.x * v.x + v.y * v.y + v.z * v.z + v.w * v.w;
#pragma unroll
  for (int d = 32; d; d >>= 1) { s += __shfl_xor(s, d, 64); s2 += __shfl_xor(s2, d, 64); }
  __shared__ float ps[4], ps2[4];
  int w = threadIdx.x >> 6;
  if ((threadIdx.x & 63) == 0) { ps[w] = s; ps2[w] = s2; }
  __syncthreads();
  s = ps[0] + ps[1] + ps[2] + ps[3];
  s2 = ps2[0] + ps2[1] + ps2[2] + ps2[3];
  float mean = s * (1.f / 1024.f);
  float var = s2 * (1.f / 1024.f) - mean * mean;
  float inv = rsqrtf(var + 1e-5f);
  float4 gv = ((const float4*)g)[threadIdx.x];
  float4 bv = ((const float4*)b)[threadIdx.x];
  ushort4 o;
  o.x = f2bf((v.x - mean) * inv * gv.x + bv.x);
  o.y = f2bf((v.y - mean) * inv * gv.y + bv.y);
  o.z = f2bf((v.z - mean) * inv * gv.z + bv.z);
  o.w = f2bf((v.w - mean) * inv * gv.w + bv.w);
  ((ushort4*)(out + (size_t)row * 1024))[threadIdx.x] = o;
}

// ---------------- bf16 GEMM: C[M][N] = A[M][K] @ Bw[N][K]^T + bias, epilogues ----------------
// EPI 0: bf16 store (all padded rows)        [QKV]
// EPI 2: gelu, bf16 store                    [FFN1]
// EPI 4: split-K=2 partial f32 store         [O-proj / FFN2 halves]
template <int EPI>
__global__ __launch_bounds__(256) void gemm_bt(const u16* __restrict__ A,
    const u16* __restrict__ Bw, const float* __restrict__ bias,
    const float* __restrict__ resid, void* __restrict__ outp,
    int N, int K, int nbx)
{
  __shared__ alignas(16) u16 sA[128 * 64];
  __shared__ alignas(16) u16 sB[128 * 64];
  int tid = threadIdx.x;
  int l = tid & 63, lg = l >> 4, li = l & 15;

  int bidx = blockIdx.x;
  int kbeg = 0, kend = K;
  float* pout = (float*)outp;
  if (EPI == 4) {
    int half = gridDim.x >> 1;
    int s = bidx >= half;
    bidx -= s * half;
    kbeg = s * (K >> 1);
    kend = kbeg + (K >> 1);
    pout += (size_t)s * MPAD * 1024;
  }
  int mb = bidx / nbx, nb = bidx % nbx;
  int m0 = mb * 128, n0 = nb * 128;
  int wv = tid >> 6;
  int wr = wv >> 1, wc = wv & 1;
  f32x4 acc[4][4] = {};
  int r_ = tid >> 3, c_ = (tid & 7) * 8;
  const u16* Ag = A + (size_t)(m0 + r_) * K + c_;
  const u16* Bg = Bw + (size_t)(n0 + r_) * K + c_;
  u16* sAb = sA + (tid & 192) * 8;   // wave-uniform staging base
  u16* sBb = sB + (tid & 192) * 8;

  for (int k0 = kbeg; k0 < kend; k0 += 64) {
    __syncthreads();
#pragma unroll
    for (int i = 0; i < 4; ++i) {
      gld16(Ag + (size_t)(i * 32) * K + k0, sAb + i * 2048);
      gld16(Bg + (size_t)(i * 32) * K + k0, sBb + i * 2048);
    }
    __syncthreads();
#pragma unroll
    for (int ks = 0; ks < 2; ++ks) {
      short8 af[4], bfr[4];
#pragma unroll
      for (int i = 0; i < 4; ++i)
        af[i] = *(const short8*)&sA[(64 * wr + 16 * i + li) * 64 + ks * 32 + lg * 8];
#pragma unroll
      for (int j = 0; j < 4; ++j)
        bfr[j] = *(const short8*)&sB[(64 * wc + 16 * j + li) * 64 + ks * 32 + lg * 8];
#pragma unroll
      for (int i = 0; i < 4; ++i)
#pragma unroll
        for (int j = 0; j < 4; ++j)
          acc[i][j] = __builtin_amdgcn_mfma_f32_16x16x32_bf16(af[i], bfr[j], acc[i][j], 0, 0, 0);
    }
  }

#pragma unroll
  for (int i = 0; i < 4; ++i) {
    int rb = m0 + 64 * wr + 16 * i + 4 * lg;
#pragma unroll
    for (int j = 0; j < 4; ++j) {
      int col = n0 + 64 * wc + 16 * j + li;
      float bia = (EPI == 4) ? 0.f : bias[col];
#pragma unroll
      for (int r = 0; r < 4; ++r) {
        int row = rb + r;
        float v = acc[i][j][r] + bia;
        if (EPI == 0) {
          ((u16*)outp)[(size_t)row * N + col] = f2bf(v);
        } else if (EPI == 2) {
          ((u16*)outp)[(size_t)row * N + col] = f2bf(gelu_f(v));
        } else {
          pout[(size_t)row * N + col] = v;
        }
      }
    }
  }
}

// ---------------- combine kernels ----------------
// O-proj: out = p0 + p1 + bo + x   (grid MV x 256)
__global__ __launch_bounds__(256) void oproj_combine(const float* __restrict__ part,
    float* __restrict__ out, const float* __restrict__ bo, const float* __restrict__ x)
{
  size_t idx = (size_t)blockIdx.x * 256 + threadIdx.x;
  const float4* p0 = (const float4*)part;
  const float4* p1 = (const float4*)(part + (size_t)MPAD * 1024);
  float4 a = p0[idx], b = p1[idx];
  float4 bb = ((const float4*)bo)[idx & 255];
  float4 xx = ((const float4*)x)[idx];
  a.x += b.x + bb.x + xx.x;
  a.y += b.y + bb.y + xx.y;
  a.z += b.z + bb.z + xx.z;
  a.w += b.w + bb.w + xx.w;
  ((float4*)out)[idx] = a;
}

// FFN2: out += p0 + p1 + b2   (grid MV x 256)
__global__ __launch_bounds__(256) void ffn2_combine(const float* __restrict__ part,
    float* __restrict__ out, const float* __restrict__ b2)
{
  size_t idx = (size_t)blockIdx.x * 256 + threadIdx.x;
  const float4* p0 = (const float4*)part;
  const float4* p1 = (const float4*)(part + (size_t)MPAD * 1024);
  float4 a = ((float4*)out)[idx];
  float4 x0 = p0[idx], x1 = p1[idx];
  float4 bb = ((const float4*)b2)[idx & 255];
  a.x += x0.x + x1.x + bb.x;
  a.y += x0.y + x1.y + bb.y;
  a.z += x0.z + x1.z + bb.z;
  a.w += x0.w + x1.w + bb.w;
  ((float4*)out)[idx] = a;
}

// ---------------- fused flash attention (precomputed fp16 ab tiles, swapped QK^T) ----------------
// grid: (b, h, qtile of 64); block 256 = 4 waves; each wave owns 16 q-rows.
// All bias/relpos/mask logic pre-baked into abt (fp16 tiles); per k-tile the 8-KB ab tile
// is staged into LDS via global_load_lds (contiguous stream) alongside K and V^T.
// QK^T computed SWAPPED: sc[f] = mfma(K, Q) -> D[row=k-local=16f+4lg+r][col=q=li], so a
// lane's 4 ab values are k-consecutive -> one 8B LDS read per f. ab LDS row is the
// block q-row (16*wv + li).
__global__ __launch_bounds__(256) void attn_fused(const u16* __restrict__ qkv,
    const u16* __restrict__ vT, const u16* __restrict__ abt,
    u16* __restrict__ o)
{
  __shared__ alignas(16) u16 k_lds[2][64 * 32];
  __shared__ alignas(16) u16 v_lds[2][32 * 64];
  __shared__ alignas(16) u16 ab_lds[2][64 * 64];
  __shared__ alignas(16) u16 p_lds[4][16][72];
  __shared__ float l_lds[4][16];
  int bid = blockIdx.x;
  int qt = bid % 9, h = (bid / 9) % NHEADS, b = bid / (9 * NHEADS);
  int tid = threadIdx.x, wv = tid >> 6, l = tid & 63, lg = l >> 4, li = l & 15;
  int q0 = qt * 64;
  int sqb = q0 + 16 * wv + 4 * lg;

  // Q fragment (B operand now; same register layout): col = li (q), k(d) = lg*8+e
  short8 qfrag = *(const short8*)(qkv + (size_t)(b * SQ + q0 + 16 * wv + li) * 3072 + h * DKH + lg * 8);

  // --- staging coords (global_load_lds: dest = lds_base + tid*16B, linear) ---
  int krow = tid >> 2;
  int kchunk = (tid & 3) ^ ((tid >> 3) & 3);
  const u16* ksrc = qkv + (size_t)(b * SQ) * 3072 + 1024 + h * DKH + kchunk * 8;  // + s*3072
  int vrow = tid >> 3;
  int vchunk = (tid & 7) ^ (vrow & 7);
  const u16* vsrc = vT + (((size_t)b * NHEADS + h) * DKH + vrow) * SVP + vchunk * 8;  // + kt*64
  // ab tile: 512 chunks; thread stages dest chunks tid and tid+256; read-side XOR swizzle
  // (chunk-in-row ^ (row&7)) -> source pre-swizzled; second round = +32 rows (row&7 invariant).
  int abrow = tid >> 3;
  int abcir = (tid & 7) ^ (abrow & 7);
  const u16* absrc0 = abt + ((size_t)(b * NHEADS + h) * 9) * SQP * 64 + (size_t)q0 * 64
                      + abrow * 64 + abcir * 8;   // + kt*SQP*64

  // K frag read offsets (A operand; row = li): swizzled to match staging
  int koff[4];
#pragma unroll
  for (int f = 0; f < 4; ++f)
    koff[f] = (16 * f + li) * 32 + ((lg ^ ((li >> 1) & 3)) * 8);
  // V frag read offsets (B operand)
  int voff[4];
#pragma unroll
  for (int u = 0; u < 4; ++u) {  // u = df*2+kk
    int df = u >> 1, kk = u & 1;
    voff[u] = (16 * df + li) * 64 + (((kk * 4 + lg) ^ (li & 7)) * 8);
  }
  // ab read offsets (bytes): row = 16*wv + li (block q-row), cols 16f+4lg..+3
  int aboff[4];
#pragma unroll
  for (int f = 0; f < 4; ++f)
    aboff[f] = (16 * wv + li) * 128 + (((2 * f + (lg >> 1)) ^ (li & 7)) << 4) + 8 * (lg & 1);

  // ---- prologue: stage tile 0 into buf 0 ----
  gld16(ksrc + (size_t)krow * 3072, (u16*)k_lds[0] + tid * 8);
  gld16(vsrc, (u16*)v_lds[0] + tid * 8);
  gld16(absrc0, (u16*)ab_lds[0] + tid * 8);
  gld16(absrc0 + 2048, (u16*)ab_lds[0] + 2048 + tid * 8);

  f32x4 o_acc[2] = {};
  float l_run = 0.f;

#pragma unroll 1
  for (int kt = 0; kt < 9; ++kt) {
    int cur = kt & 1;
    __syncthreads();  // stage(kt) landed; prev readers done
    if (kt < 8) {     // stage tile kt+1 -> other buffer; flies under this tile's compute
      int s = (kt + 1) * 64 + krow; if (s > 512) s = 512;
      gld16(ksrc + (size_t)s * 3072, (u16*)k_lds[cur ^ 1] + tid * 8);
      gld16(vsrc + (size_t)(kt + 1) * 64, (u16*)v_lds[cur ^ 1] + tid * 8);
      const u16* abn = absrc0 + (size_t)(kt + 1) * SQP * 64;
      gld16(abn, (u16*)ab_lds[cur ^ 1] + tid * 8);
      gld16(abn + 2048, (u16*)ab_lds[cur ^ 1] + 2048 + tid * 8);
    }
    const u16* kbp = k_lds[cur];
    const u16* vbf = v_lds[cur];
    const char* abl = (const char*)ab_lds[cur];

    // QK^T swapped: D[k-local][q]
    f32x4 sc[4];
    __builtin_amdgcn_s_setprio(1);
#pragma unroll
    for (int f = 0; f < 4; ++f) {
      short8 kf = *(const short8*)&kbp[koff[f]];
      f32x4 z = {};
      sc[f] = __builtin_amdgcn_mfma_f32_16x16x32_bf16(kf, qfrag, z, 0, 0, 0);
    }
    __builtin_amdgcn_s_setprio(0);

    // add ab (fp16 from LDS, 4 consecutive k per lane), exp, accumulate l, pack P
#pragma unroll
    for (int f = 0; f < 4; ++f) {
      uint2 uu = *(const uint2*)(abl + aboff[f]);
      float a0 = h2f((u16)(uu.x & 0xffffu));
      float a1 = h2f((u16)(uu.x >> 16));
      float a2 = h2f((u16)(uu.y & 0xffffu));
      float a3 = h2f((u16)(uu.y >> 16));
      float p0 = __expf(sc[f][0] + a0);
      float p1 = __expf(sc[f][1] + a1);
      float p2 = __expf(sc[f][2] + a2);
      float p3 = __expf(sc[f][3] + a3);
      l_run += (p0 + p1) + (p2 + p3);
      uint2 pk;
      pk.x = (u32)f2bf(p0) | ((u32)f2bf(p1) << 16);
      pk.y = (u32)f2bf(p2) | ((u32)f2bf(p3) << 16);
      *(uint2*)((char*)&p_lds[wv][0][0] + li * 144 + f * 32 + lg * 8) = pk;
    }

    // PV: out[16 q][32 d] += P[16][64] @ V[64][32]  (p_lds per-wave: no barrier)
    __builtin_amdgcn_s_setprio(1);
#pragma unroll
    for (int kk = 0; kk < 2; ++kk) {
      short8 pa = *(const short8*)&p_lds[wv][li][kk * 32 + lg * 8];
#pragma unroll
      for (int df = 0; df < 2; ++df) {
        short8 vb = *(const short8*)&vbf[voff[df * 2 + kk]];
        o_acc[df] = __builtin_amdgcn_mfma_f32_16x16x32_bf16(pa, vb, o_acc[df], 0, 0, 0);
      }
    }
    __builtin_amdgcn_s_setprio(0);
  }

  // ---- epilogue: reduce l over the 4 lg copies (q = li), redistribute, store ----
  float s = l_run;
  s += __shfl_xor(s, 16, 64);
  s += __shfl_xor(s, 32, 64);
  if (l < 16) l_lds[wv][l] = s;
  float lr[4];
#pragma unroll
  for (int r = 0; r < 4; ++r) lr[r] = l_lds[wv][4 * lg + r];
#pragma unroll
  for (int df = 0; df < 2; ++df)
#pragma unroll
    for (int r = 0; r < 4; ++r) {
      int s_q = sqb + r;
      if (s_q <= 512)
        o[(size_t)(b * SQ + s_q) * 1024 + h * DKH + 16 * df + li] = f2bf(o_acc[df][r] / lr[r]);
    }
}

extern "C" void kernel_launch(void* const* d_in, const int* in_sizes, int n_in,
                              void* d_out, int out_size, void* d_ws, size_t ws_size,
                              hipStream_t stream) {
  const float* x        = (const float*)d_in[0];
  const float* attn_bias= (const float*)d_in[1];
  const float* rel_emb  = (const float*)d_in[2];
  const float* Wq = (const float*)d_in[3];
  const float* bq = (const float*)d_in[4];
  const float* Wk = (const float*)d_in[5];
  const float* bk = (const float*)d_in[6];
  const float* Wv = (const float*)d_in[7];
  const float* bv = (const float*)d_in[8];
  const float* Wo = (const float*)d_in[9];
  const float* bo = (const float*)d_in[10];
  const float* W1 = (const float*)d_in[11];
  const float* b1 = (const float*)d_in[12];
  const float* W2 = (const float*)d_in[13];
  const float* b2 = (const float*)d_in[14];
  const float* ln1g = (const float*)d_in[15];
  const float* ln1b = (const float*)d_in[16];
  const float* ln2g = (const float*)d_in[17];
  const float* ln2b = (const float*)d_in[18];
  const int*   rel_pos = (const int*)d_in[19];
  float* out = (float*)d_out;

  char* ws = (char*)d_ws;
  size_t off = 0;
  auto alloc = [&](size_t bytes) { char* p = ws + off; off += (bytes + 255) & ~(size_t)255; return p; };
  u16* w_qkvT = (u16*)alloc((size_t)3072 * 1024 * 2);
  u16* w_oT   = (u16*)alloc((size_t)1024 * 1024 * 2);
  u16* w_1T   = (u16*)alloc((size_t)4096 * 1024 * 2);
  u16* w_2T   = (u16*)alloc((size_t)1024 * 4096 * 2);
  float* bias_qkv = (float*)alloc(3072 * 4);
  u16* ybuf = (u16*)alloc((size_t)MPAD * 1024 * 2);   // y1, later y2
  u16* obuf = (u16*)alloc((size_t)MPAD * 1024 * 2);   // attention output
  u16* vTb  = (u16*)alloc((size_t)8 * NHEADS * DKH * SVP * 2);  // V^T [b][h][d][SVP]
  u16* big  = (u16*)alloc((size_t)MPAD * 4096 * 2);   // qkv [MPAD][3072], later ffn1 [MPAD][4096]
  float* part = (float*)alloc((size_t)2 * MPAD * 1024 * 4);     // split-K partials (O-proj, FFN2)
  u16* abt  = (u16*)alloc((size_t)256 * 9 * SQP * 64 * 2);      // baked bias tiles (fp16), 170 MB

  const float scale = 0.17677669529663689f;  // 32^-0.5
  dim3 blk(256);

  prep_ab<<<dim3(256, 36), blk, 0, stream>>>(attn_bias, rel_pos, rel_emb, abt);
  transpose_cast_k<<<dim3(32, 32), blk, 0, stream>>>(Wq, w_qkvT, 1024, 1024, scale);
  transpose_cast_k<<<dim3(32, 32), blk, 0, stream>>>(Wk, w_qkvT + (size_t)1024 * 1024, 1024, 1024, 1.f);
  transpose_cast_k<<<dim3(32, 32), blk, 0, stream>>>(Wv, w_qkvT + (size_t)2048 * 1024, 1024, 1024, 1.f);
  transpose_cast_k<<<dim3(32, 32), blk, 0, stream>>>(Wo, w_oT, 1024, 1024, 1.f);
  transpose_cast_k<<<dim3(128, 32), blk, 0, stream>>>(W1, w_1T, 1024, 4096, 1.f);
  transpose_cast_k<<<dim3(32, 128), blk, 0, stream>>>(W2, w_2T, 4096, 1024, 1.f);
  prep_bias_k<<<12, blk, 0, stream>>>(bq, bk, bv, bias_qkv, scale);

  ln_k<<<MV, blk, 0, stream>>>(x, ln1g, ln1b, ybuf);
  gemm_bt<0><<<33 * 24, blk, 0, stream>>>(ybuf, w_qkvT, bias_qkv, nullptr, big, 3072, 1024, 24);
  vtrans_k<<<dim3(18, NHEADS, 8), blk, 0, stream>>>(big, vTb);
  attn_fused<<<8 * NHEADS * 9, blk, 0, stream>>>(big, vTb, abt, obuf);
  gemm_bt<4><<<33 * 8 * 2, blk, 0, stream>>>(obuf, w_oT, bo, nullptr, part, 1024, 1024, 8);
  oproj_combine<<<MV, blk, 0, stream>>>(part, out, bo, x);
  ln_k<<<MV, blk, 0, stream>>>(out, ln2g, ln2b, ybuf);
  gemm_bt<2><<<33 * 32, blk, 0, stream>>>(ybuf, w_1T, b1, nullptr, big, 4096, 1024, 32);
  gemm_bt<4><<<33 * 8 * 2, blk, 0, stream>>>(big, w_2T, b2, nullptr, part, 1024, 4096, 8);
  ffn2_combine<<<MV, blk, 0, stream>>>(part, out, b2);
}